// Round 5
// baseline (276.906 us; speedup 1.0000x reference)
//
#include <hip/hip_runtime.h>

#define H 1024
#define QD 16
#define BATCH 4
#define SEQ 2048
#define MROWS 8192  // BATCH*SEQ
#define KCH 32      // fused_attn k-chunk

typedef __bf16 bf16x8 __attribute__((ext_vector_type(8)));
typedef __bf16 bf16x4 __attribute__((ext_vector_type(4)));
typedef float f32x4 __attribute__((ext_vector_type(4)));

__device__ __forceinline__ void async_g2l_16(const void* g, void* l) {
  __builtin_amdgcn_global_load_lds(
      (const __attribute__((address_space(1))) unsigned int*)g,
      (__attribute__((address_space(3))) unsigned int*)l, 16, 0, 0);
}

// ---------------- fp32 -> bf16 hi/lo split (x) ----------------
__global__ __launch_bounds__(256) void cvt_split(const float* __restrict__ src,
                                                 __bf16* __restrict__ hi,
                                                 __bf16* __restrict__ lo, int n) {
  int i = (blockIdx.x * 256 + threadIdx.x) * 4;
  if (i < n) {
    float4 f = *(const float4*)(src + i);
    bf16x4 h, l;
    h[0] = (__bf16)f.x; l[0] = (__bf16)(f.x - (float)h[0]);
    h[1] = (__bf16)f.y; l[1] = (__bf16)(f.y - (float)h[1]);
    h[2] = (__bf16)f.z; l[2] = (__bf16)(f.z - (float)h[2]);
    h[3] = (__bf16)f.w; l[3] = (__bf16)(f.w - (float)h[3]);
    *(bf16x4*)(hi + i) = h;
    *(bf16x4*)(lo + i) = l;
  }
}

// ---------------- fp32 [R][C] -> bf16 transposed [C][R] ----------------
__global__ __launch_bounds__(256) void transpose_cvt_f32_bf16(
    const float* __restrict__ src, __bf16* __restrict__ dst, int R, int C) {
  __shared__ float t[32][33];
  const int rb = blockIdx.y * 32, cb = blockIdx.x * 32;
  const int c = threadIdx.x & 31;
  const int r0 = threadIdx.x >> 5;
#pragma unroll
  for (int rr = r0; rr < 32; rr += 8)
    t[rr][c] = src[(long)(rb + rr) * C + cb + c];
  __syncthreads();
#pragma unroll
  for (int rr = r0; rr < 32; rr += 8)
    dst[(long)(cb + rr) * R + rb + c] = (__bf16)t[c][rr];
}

// ---------------- CqkT (Bt layout [32][1024]) in bf16 hi/lo ----------------
__global__ __launch_bounds__(256) void k2_cqk(const float* __restrict__ Wq,
                                              const float* __restrict__ Wk,
                                              const float* __restrict__ We,
                                              __bf16* __restrict__ Cth,
                                              __bf16* __restrict__ Ctl) {
  const int gw = blockIdx.x * 4 + (threadIdx.x >> 6);  // 0..2047
  const int lane = threadIdx.x & 63;
  const int mat = gw & 1, k = gw >> 1;
  const float* Wrow = (mat ? Wk : Wq) + (long)k * H;
  const int col = lane & 15, q4 = lane >> 4;
  float acc = 0.f;
  for (int n0 = 0; n0 < 256; ++n0) {
    int n = q4 * 256 + n0;
    acc += Wrow[n] * We[n * QD + col];
  }
  acc += __shfl_xor(acc, 16);
  acc += __shfl_xor(acc, 32);
  if (lane < 16) {
    __bf16 hi = (__bf16)acc;
    __bf16 lo = (__bf16)(acc - (float)hi);
    long idx = (long)(mat * 16 + col) * H + k;
    Cth[idx] = hi;
    Ctl[idx] = lo;
  }
}

// ---------------- dvec[j] = (bq|bk)@We + be ----------------
__global__ void k2b_dvec(const float* __restrict__ bq, const float* __restrict__ bk,
                         const float* __restrict__ We, const float* __restrict__ be,
                         float* __restrict__ dvec) {
  int j = threadIdx.x;
  if (j < 32) {
    int mat = j >> 4, col = j & 15;
    const float* b = mat ? bk : bq;
    float acc = be[col];
    for (int n = 0; n < H; ++n) acc += b[n] * We[n * QD + col];
    dvec[j] = acc;
  }
}

// ---------------- embed via MFMA (hi/lo split), fused normalize ----------------
// Outputs bf16 qq/kk in [S][32] layout with zero-padded upper K half.
// qq is additionally scaled by sqrt(log2 e) so attn can use raw exp2.
__global__ __launch_bounds__(256) void k3_embed_mfma(
    const __bf16* __restrict__ xh, const __bf16* __restrict__ xl,
    const __bf16* __restrict__ Cth, const __bf16* __restrict__ Ctl,
    const float* __restrict__ dvec, __bf16* __restrict__ qq32,
    __bf16* __restrict__ kk32) {
  __shared__ __bf16 Ah[32 * 64];
  __shared__ __bf16 Al[32 * 64];
  __shared__ __bf16 Bh[32 * 64];
  __shared__ __bf16 Bl[32 * 64];
  const int tid = threadIdx.x;
  const int lane = tid & 63;
  const int w = tid >> 6;
  const int rowhalf = w >> 1;  // 0/1 -> rows 0-15 / 16-31
  const int ntile = w & 1;     // 0 -> qq, 1 -> kk
  const int l15 = lane & 15, quad = lane >> 4;
  const long rowBase = (long)blockIdx.x * 32;

  const int srow = tid >> 3;                       // 0..31 (LDS row)
  const int segsw = ((tid & 7) ^ (srow & 7)) * 8;  // swizzled global k-seg
  const __bf16* agh = xh + (rowBase + srow) * H + segsw;
  const __bf16* agl = xl + (rowBase + srow) * H + segsw;
  const __bf16* bgh = Cth + (long)srow * H + segsw;
  const __bf16* bgl = Ctl + (long)srow * H + segsw;
  __bf16* lah = &Ah[srow * 64 + (tid & 7) * 8];
  __bf16* lal = &Al[srow * 64 + (tid & 7) * 8];
  __bf16* lbh = &Bh[srow * 64 + (tid & 7) * 8];
  __bf16* lbl = &Bl[srow * 64 + (tid & 7) * 8];

  f32x4 acc;
  acc[0] = 0.f; acc[1] = 0.f; acc[2] = 0.f; acc[3] = 0.f;
  const int arow = (rowhalf * 16 + l15) * 64;
  const int brow = (ntile * 16 + l15) * 64;
  const int h7 = l15 & 7;

  for (int k0 = 0; k0 < H; k0 += 64) {
    async_g2l_16(agh + k0, lah);
    async_g2l_16(agl + k0, lal);
    async_g2l_16(bgh + k0, lbh);
    async_g2l_16(bgl + k0, lbl);
    __syncthreads();
#pragma unroll
    for (int s = 0; s < 2; ++s) {
      const int slot = ((s * 4 + quad) ^ h7) * 8;
      bf16x8 fah = *(const bf16x8*)&Ah[arow + slot];
      bf16x8 fal = *(const bf16x8*)&Al[arow + slot];
      bf16x8 fbh = *(const bf16x8*)&Bh[brow + slot];
      bf16x8 fbl = *(const bf16x8*)&Bl[brow + slot];
      acc = __builtin_amdgcn_mfma_f32_16x16x32_bf16(fah, fbh, acc, 0, 0, 0);
      acc = __builtin_amdgcn_mfma_f32_16x16x32_bf16(fal, fbh, acc, 0, 0, 0);
      acc = __builtin_amdgcn_mfma_f32_16x16x32_bf16(fah, fbl, acc, 0, 0, 0);
    }
    __syncthreads();
  }

  const float dv = dvec[ntile * 16 + l15];
  // fold sqrt(log2 e) into qq so S^2 arrives pre-scaled for exp2
  const float osc = ntile ? 1.0f : 1.20112240878f;
  __bf16* outp = ntile ? kk32 : qq32;
#pragma unroll
  for (int r = 0; r < 4; ++r) {
    float z = acc[r] + dv;
    float s2 = z * z;
    s2 += __shfl_xor(s2, 1);
    s2 += __shfl_xor(s2, 2);
    s2 += __shfl_xor(s2, 4);
    s2 += __shfl_xor(s2, 8);
    float val = z * rsqrtf(s2 + 1e-8f) * osc;
    long row = rowBase + rowhalf * 16 + quad * 4 + r;
    outp[row * 32 + l15] = (__bf16)val;
    outp[row * 32 + 16 + l15] = (__bf16)0.f;  // zero pad K 16->32
  }
}

// ---------------- fused attention, 8 waves, 64q x 256h tile ----------------
// KCH=32, V triple-buffered (3x16KB), P double-buffered (2x4KB) -> 57KB LDS,
// 2 blocks/CU, 512 blocks, 4 waves/SIMD. One s_barrier + counted vmcnt(3)
// per chunk (2 V-stage + 1 kk load stay in flight). XCD-aware remap: each
// XCD owns two (h,b) V panels and all 32 q-blocks sharing them (L2-resident).
// 16B-granule XOR swizzle gi^((row>>1)&3) on 64B rows: 2-way bank alias (free).
// Buffer safety (as R3): stage(t+1)->buf (t+1)%3, PV(t) reads t%3; max wave
// skew is one barrier, (t+2)%3 != t%3; P halves alternate.
__global__ __launch_bounds__(512, 4) void fused_attn(
    const __bf16* __restrict__ qq32, const __bf16* __restrict__ kk32,
    const __bf16* __restrict__ v_t, __bf16* __restrict__ attn) {
  __shared__ __bf16 Vlds[3][256 * KCH];  // 48KB
  __shared__ __bf16 Plds[2][64 * KCH];   // 8KB
  __shared__ float rsum2[64 * 2];
  const int tid = threadIdx.x;
  const int lane = tid & 63;
  const int w = tid >> 6;  // 0..7
  const int l15 = lane & 15, quad = lane >> 4;
  const int ws_k = w & 1, ws_q = w >> 1;  // S-phase: 16k x 16q
  const int wp_h = w & 3, wp_q = w >> 2;  // PV-phase: 64h x 32q

  // XCD-aware remap: flat id -> (xcd, seq); each XCD gets 2 (h,b) panels.
  const int bid = blockIdx.x;            // 0..511
  const int xcd = bid & 7, s = bid >> 3; // s: 0..63
  const int panel = xcd * 2 + (s >> 5);  // 0..15
  const int b = panel >> 2;
  const long hbase = (long)(panel & 3) * 256;
  const long qbase = (long)(s & 31) * 64;

  // qq B-frag: constant across the k-loop (16 q rows per wave)
  bf16x8 bq = *(const bf16x8*)(qq32 +
      ((long)b * SEQ + qbase + ws_q * 16 + l15) * 32 + quad * 8);
  const __bf16* kkb = kk32 + ((long)b * SEQ + ws_k * 16 + l15) * 32 + quad * 8;

  // V staging: 256h x 32k per chunk = 1024 16B-granules, 2 per thread.
  // LDS dest is wave-linear (tid*16B); global source pre-swizzled.
  const int r0s = tid >> 2, gi0 = tid & 3;
  const int sg0 = gi0 ^ ((r0s >> 1) & 3);  // same for r0s+128
  const __bf16* vg0 = v_t + (long)b * H * SEQ + (hbase + r0s) * SEQ + sg0 * 8;
  const __bf16* vg1 = vg0 + (long)128 * SEQ;

  f32x4 acc[2][4];
#pragma unroll
  for (int i = 0; i < 2; ++i)
#pragma unroll
    for (int j = 0; j < 4; ++j) {
      acc[i][j][0] = 0.f; acc[i][j][1] = 0.f; acc[i][j][2] = 0.f; acc[i][j][3] = 0.f;
    }
  float rsPart = 0.f;

  // Constant LDS offsets (elems): P write, P read (x2), V read (x4)
  const int qrow = ws_q * 16 + l15;
  const int glin = ws_k * 2 + (quad >> 1);
  const int pwOff = qrow * KCH + ((glin ^ ((qrow >> 1) & 3)) << 3) + (quad & 1) * 4;
  int apOff[2], bvOff[4];
#pragma unroll
  for (int i = 0; i < 2; ++i) {
    const int pq = wp_q * 32 + i * 16 + l15;
    apOff[i] = pq * KCH + ((quad ^ ((pq >> 1) & 3)) << 3);
  }
#pragma unroll
  for (int j = 0; j < 4; ++j) {
    const int vr = wp_h * 64 + j * 16 + l15;
    bvOff[j] = vr * KCH + ((quad ^ ((vr >> 1) & 3)) << 3);
  }

  // prologue: stage chunk 0 -> buf0 (2 vmem), load kk frag chunk 0 (1 vmem)
  async_g2l_16(vg0, &Vlds[0][tid * 8]);
  async_g2l_16(vg1, &Vlds[0][(tid + 512) * 8]);
  bf16x8 ak = *(const bf16x8*)kkb;

  int vcur = 0, vnxt = 1;
  for (int t = 0; t < SEQ / KCH; ++t) {
    const int kn = ((t + 1) & (SEQ / KCH - 1)) * KCH;  // wraps (dummy) at last
    // 1) issue stage of chunk t+1 (2 vmem ops)
    async_g2l_16(vg0 + kn, &Vlds[vnxt][tid * 8]);
    async_g2l_16(vg1 + kn, &Vlds[vnxt][(tid + 512) * 8]);
    // 2) prefetch kk frag for chunk t+1 (1 vmem op)
    bf16x8 akn = *(const bf16x8*)(kkb + (long)kn * 32);

    // 3) S-phase (chunk t): 1 MFMA -> exp2 -> Plds[t&1]
    __bf16* Pw = Plds[t & 1];
    {
      f32x4 sv;
      sv[0] = 0.f; sv[1] = 0.f; sv[2] = 0.f; sv[3] = 0.f;
      sv = __builtin_amdgcn_mfma_f32_16x16x32_bf16(ak, bq, sv, 0, 0, 0);
      bf16x4 pw;
      float part = 0.f;
#pragma unroll
      for (int r = 0; r < 4; ++r) {
        float wgt = exp2f(sv[r] * sv[r]);  // qq carries sqrt(log2e)
        part += wgt;
        pw[r] = (__bf16)wgt;
      }
      rsPart += part;
      *(bf16x4*)&Pw[pwOff] = pw;
    }

    // 4) P writes visible; chunk-t V staged (3 younger vmem stay in flight)
    asm volatile("s_waitcnt lgkmcnt(0)" ::: "memory");
    asm volatile("s_waitcnt vmcnt(3)" ::: "memory");
    __builtin_amdgcn_sched_barrier(0);
    __builtin_amdgcn_s_barrier();

    // 5) PV: acc += P[64q x 32k] @ V[256h x 32k]^T   (wave: 32q x 64h)
    const __bf16* Vr = Vlds[vcur];
    bf16x8 ap[2], bv[4];
#pragma unroll
    for (int i = 0; i < 2; ++i) ap[i] = *(const bf16x8*)&Pw[apOff[i]];
#pragma unroll
    for (int j = 0; j < 4; ++j) bv[j] = *(const bf16x8*)&Vr[bvOff[j]];
    __builtin_amdgcn_s_setprio(1);
#pragma unroll
    for (int i = 0; i < 2; ++i)
#pragma unroll
      for (int j = 0; j < 4; ++j)
        acc[i][j] =
            __builtin_amdgcn_mfma_f32_16x16x32_bf16(ap[i], bv[j], acc[i][j], 0, 0, 0);
    __builtin_amdgcn_s_setprio(0);

    // 6) rotate V buffers; advance kk frag
    const int third = 3 - vcur - vnxt;
    vcur = vnxt;
    vnxt = third;
    ak = akn;
  }

  // rowsum: reduce lane partials over quads, combine two k-halves via LDS
  {
    float vs = rsPart;
    vs += __shfl_xor(vs, 16);
    vs += __shfl_xor(vs, 32);
    if (lane < 16) rsum2[qrow * 2 + ws_k] = vs;
  }
  __syncthreads();  // also drains the final dummy stage

  float rinv[2][4];
#pragma unroll
  for (int i = 0; i < 2; ++i)
#pragma unroll
    for (int r = 0; r < 4; ++r) {
      int row = wp_q * 32 + i * 16 + quad * 4 + r;
      rinv[i][r] = 1.0f / (rsum2[row * 2] + rsum2[row * 2 + 1]);
    }

  __bf16* ob = attn + ((long)b * SEQ + qbase) * H + hbase;
#pragma unroll
  for (int i = 0; i < 2; ++i)
#pragma unroll
    for (int j = 0; j < 4; ++j) {
      const int colL = wp_h * 64 + j * 16 + l15;
#pragma unroll
      for (int r = 0; r < 4; ++r) {
        const int rowL = wp_q * 32 + i * 16 + quad * 4 + r;
        ob[(long)rowL * H + colL] = (__bf16)(acc[i][j][r] * rinv[i][r]);
      }
    }
}

// ---------------- m97-style GEMM + XOR-swizzled LDS: C = A @ Bt^T (+bias) ----
// OUTMODE: 0 = fp32 row-major, 1 = bf16 row-major, 2 = bf16 transposed batched
//          (Cout layout [BATCH][N][SEQ], rows are per-batch: row = b*SEQ + rb)
template <int OUTMODE, int HASBIAS>
__global__ __launch_bounds__(256) void gemm_bt(
    const __bf16* __restrict__ A, const __bf16* __restrict__ Bt,
    void* __restrict__ Cout, const float* __restrict__ bias, int M, int N, int K) {
  __shared__ __bf16 Alds[128 * 64];
  __shared__ __bf16 Blds[128 * 64];
  const int tid = threadIdx.x;
  const int lane = tid & 63;
  const int w = tid >> 6;
  const int wm = w >> 1, wn = w & 1;
  const int l15 = lane & 15, quad = lane >> 4;
  const long rowBase = (long)blockIdx.y * 128;
  const long colBase = (long)blockIdx.x * 128;

  const int srow = lane >> 3;                 // 0..7
  const int segsw = ((lane & 7) ^ srow) * 8;  // swizzled global k-seg

  const __bf16* ag[4];
  const __bf16* bg[4];
  __bf16* as_[4];
  __bf16* bs_[4];
#pragma unroll
  for (int j = 0; j < 4; ++j) {
    int r = j * 32 + w * 8;
    ag[j] = A + (rowBase + r + srow) * (long)K + segsw;
    bg[j] = Bt + (colBase + r + srow) * (long)K + segsw;
    as_[j] = &Alds[r * 64 + (lane & 7) * 8];
    bs_[j] = &Blds[r * 64 + (lane & 7) * 8];
  }

  f32x4 acc[4][4];
#pragma unroll
  for (int i = 0; i < 4; ++i)
#pragma unroll
    for (int j = 0; j < 4; ++j) {
      acc[i][j][0] = 0.f; acc[i][j][1] = 0.f; acc[i][j][2] = 0.f; acc[i][j][3] = 0.f;
    }

  const int h7 = l15 & 7;

  for (int k0 = 0; k0 < K; k0 += 64) {
#pragma unroll
    for (int j = 0; j < 4; ++j) {
      async_g2l_16(ag[j], as_[j]);
      async_g2l_16(bg[j], bs_[j]);
      ag[j] += 64;
      bg[j] += 64;
    }
    __syncthreads();
#pragma unroll
    for (int s = 0; s < 2; ++s) {
      const int slot = ((s * 4 + quad) ^ h7) * 8;
      bf16x8 af[4], bfv[4];
#pragma unroll
      for (int i = 0; i < 4; ++i) {
        af[i] = *(const bf16x8*)&Alds[(wm * 64 + i * 16 + l15) * 64 + slot];
        bfv[i] = *(const bf16x8*)&Blds[(wn * 64 + i * 16 + l15) * 64 + slot];
      }
#pragma unroll
      for (int i = 0; i < 4; ++i)
#pragma unroll
        for (int j = 0; j < 4; ++j)
          acc[i][j] =
              __builtin_amdgcn_mfma_f32_16x16x32_bf16(af[i], bfv[j], acc[i][j], 0, 0, 0);
    }
    __syncthreads();
  }

  const long crow0 = rowBase + wm * 64 + quad * 4;
  const long ccol0 = colBase + wn * 64 + l15;
#pragma unroll
  for (int i = 0; i < 4; ++i) {
#pragma unroll
    for (int j = 0; j < 4; ++j) {
      long col = ccol0 + j * 16;
      float bb = HASBIAS ? bias[col] : 0.f;
      if (OUTMODE == 2) {
        long row0 = crow0 + i * 16;          // 4 consecutive rows, same batch
        int bz = (int)(row0 >> 11);          // row / SEQ
        long rb = row0 & (SEQ - 1);
        bf16x4 pv;
#pragma unroll
        for (int r = 0; r < 4; ++r) pv[r] = (__bf16)(acc[i][j][r] + bb);
        *(bf16x4*)&((__bf16*)Cout)[((long)bz * N + col) * SEQ + rb] = pv;
      } else {
#pragma unroll
        for (int r = 0; r < 4; ++r) {
          long row = crow0 + i * 16 + r;
          float val = acc[i][j][r] + bb;
          if (OUTMODE == 0)
            ((float*)Cout)[row * N + col] = val;
          else
            ((__bf16*)Cout)[row * N + col] = (__bf16)val;
        }
      }
    }
  }
}

extern "C" void kernel_launch(void* const* d_in, const int* in_sizes, int n_in,
                              void* d_out, int out_size, void* d_ws, size_t ws_size,
                              hipStream_t stream) {
  const float* x = (const float*)d_in[0];
  const float* Wq = (const float*)d_in[1];
  const float* bq = (const float*)d_in[2];
  const float* Wk = (const float*)d_in[3];
  const float* bk = (const float*)d_in[4];
  const float* Wv = (const float*)d_in[5];
  const float* bv = (const float*)d_in[6];
  const float* We = (const float*)d_in[7];
  const float* be = (const float*)d_in[8];
  const float* Wo = (const float*)d_in[9];
  const float* bo = (const float*)d_in[10];
  float* out = (float*)d_out;

  char* ws = (char*)d_ws;
  size_t o = 0;
  auto alloc = [&](size_t n) {
    size_t r = o;
    o += (n + 255) & ~(size_t)255;
    return r;
  };
  __bf16* xbf = (__bf16*)(ws + alloc((size_t)MROWS * H * 2));  // x hi
  __bf16* v_t = (__bf16*)(ws + alloc((size_t)MROWS * H * 2));  // v^T [B][H][S]
  __bf16* attn = (__bf16*)(ws + alloc((size_t)MROWS * H * 2));
  __bf16* Wvt = (__bf16*)(ws + alloc((size_t)H * H * 2));
  __bf16* Wot = (__bf16*)(ws + alloc((size_t)H * H * 2));
  __bf16* Cth = (__bf16*)(ws + alloc((size_t)32 * H * 2));
  __bf16* Ctl = (__bf16*)(ws + alloc((size_t)32 * H * 2));
  float* dvec = (float*)(ws + alloc(32 * 4));
  __bf16* qq32 = (__bf16*)(ws + alloc((size_t)MROWS * 32 * 2));
  __bf16* kk32 = (__bf16*)(ws + alloc((size_t)MROWS * 32 * 2));
  // Alias (stream-ordered lifetime separation):
  __bf16* xlo = attn;  // x lo part: dead before attn is written (fused_attn)
  if (ws_size < o) return;

  // 1) x -> bf16 hi/lo split
  cvt_split<<<MROWS * H / 1024, 256, 0, stream>>>(x, xbf, xlo, MROWS * H);
  // 2) Wv^T, Wo^T as bf16
  transpose_cvt_f32_bf16<<<dim3(32, 32), 256, 0, stream>>>(Wv, Wvt, H, H);
  transpose_cvt_f32_bf16<<<dim3(32, 32), 256, 0, stream>>>(Wo, Wot, H, H);
  // 3) collapsed embed matrices (bf16 hi/lo, Bt layout) + bias fold
  k2_cqk<<<512, 256, 0, stream>>>(Wq, Wk, We, Cth, Ctl);
  k2b_dvec<<<1, 64, 0, stream>>>(bq, bk, We, be, dvec);
  // 4) unit-norm quantum embeds via MFMA -> bf16 [S][32] zero-padded
  k3_embed_mfma<<<MROWS / 32, 256, 0, stream>>>(xbf, xlo, Cth, Ctl, dvec, qq32, kk32);
  // 5) v = x@Wv + bv, written TRANSPOSED per batch -> v_t[b][h][s]
  gemm_bt<2, 1><<<dim3(8, 64), 256, 0, stream>>>(xbf, Wvt, v_t, bv, MROWS, H, H);
  // 6) fused: S^T once per 256h -> exp2(S'^2) -> P@v/rowsum  (bf16 out)
  fused_attn<<<512, 512, 0, stream>>>(qq32, kk32, v_t, attn);
  // 7) out = attended @ Wo + bo  (fp32 out)
  gemm_bt<0, 1><<<dim3(8, 64), 256, 0, stream>>>(attn, Wot, out, bo, MROWS, H, H);
}

// Round 6
// 240.485 us; speedup vs baseline: 1.1514x; 1.1514x over previous
//
#include <hip/hip_runtime.h>

#define H 1024
#define QD 16
#define BATCH 4
#define SEQ 2048
#define MROWS 8192  // BATCH*SEQ
#define KCH 64      // fused_attn k-chunk

typedef __bf16 bf16x8 __attribute__((ext_vector_type(8)));
typedef __bf16 bf16x4 __attribute__((ext_vector_type(4)));
typedef float f32x4 __attribute__((ext_vector_type(4)));

__device__ __forceinline__ void async_g2l_16(const void* g, void* l) {
  __builtin_amdgcn_global_load_lds(
      (const __attribute__((address_space(1))) unsigned int*)g,
      (__attribute__((address_space(3))) unsigned int*)l, 16, 0, 0);
}

// ---------------- fp32 -> bf16 hi/lo split (x) ----------------
__global__ __launch_bounds__(256) void cvt_split(const float* __restrict__ src,
                                                 __bf16* __restrict__ hi,
                                                 __bf16* __restrict__ lo, int n) {
  int i = (blockIdx.x * 256 + threadIdx.x) * 4;
  if (i < n) {
    float4 f = *(const float4*)(src + i);
    bf16x4 h, l;
    h[0] = (__bf16)f.x; l[0] = (__bf16)(f.x - (float)h[0]);
    h[1] = (__bf16)f.y; l[1] = (__bf16)(f.y - (float)h[1]);
    h[2] = (__bf16)f.z; l[2] = (__bf16)(f.z - (float)h[2]);
    h[3] = (__bf16)f.w; l[3] = (__bf16)(f.w - (float)h[3]);
    *(bf16x4*)(hi + i) = h;
    *(bf16x4*)(lo + i) = l;
  }
}

// ---------------- fp32 [R][C] -> bf16 transposed [C][R] ----------------
__global__ __launch_bounds__(256) void transpose_cvt_f32_bf16(
    const float* __restrict__ src, __bf16* __restrict__ dst, int R, int C) {
  __shared__ float t[32][33];
  const int rb = blockIdx.y * 32, cb = blockIdx.x * 32;
  const int c = threadIdx.x & 31;
  const int r0 = threadIdx.x >> 5;
#pragma unroll
  for (int rr = r0; rr < 32; rr += 8)
    t[rr][c] = src[(long)(rb + rr) * C + cb + c];
  __syncthreads();
#pragma unroll
  for (int rr = r0; rr < 32; rr += 8)
    dst[(long)(cb + rr) * R + rb + c] = (__bf16)t[c][rr];
}

// ---------------- CqkT (Bt layout [32][1024]) in bf16 hi/lo ----------------
// v2: float4 W reads (4x fewer W load instrs); We stays scalar (L1-hot 64KB).
__global__ __launch_bounds__(256) void k2_cqk(const float* __restrict__ Wq,
                                              const float* __restrict__ Wk,
                                              const float* __restrict__ We,
                                              __bf16* __restrict__ Cth,
                                              __bf16* __restrict__ Ctl) {
  const int gw = blockIdx.x * 4 + (threadIdx.x >> 6);  // 0..2047
  const int lane = threadIdx.x & 63;
  const int mat = gw & 1, k = gw >> 1;
  const float* Wrow = (mat ? Wk : Wq) + (long)k * H;
  const int col = lane & 15, q4 = lane >> 4;
  const float* wp = Wrow + q4 * 256;
  const float* wep = We + (long)q4 * 256 * QD + col;
  float acc = 0.f;
#pragma unroll 4
  for (int n0 = 0; n0 < 256; n0 += 4) {
    float4 w4 = *(const float4*)(wp + n0);
    acc += w4.x * wep[(n0 + 0) * QD];
    acc += w4.y * wep[(n0 + 1) * QD];
    acc += w4.z * wep[(n0 + 2) * QD];
    acc += w4.w * wep[(n0 + 3) * QD];
  }
  acc += __shfl_xor(acc, 16);
  acc += __shfl_xor(acc, 32);
  if (lane < 16) {
    __bf16 hi = (__bf16)acc;
    __bf16 lo = (__bf16)(acc - (float)hi);
    long idx = (long)(mat * 16 + col) * H + k;
    Cth[idx] = hi;
    Ctl[idx] = lo;
  }
}

// ---------------- dvec[j] = (bq|bk)@We + be (parallel v2) ----------------
__global__ __launch_bounds__(512) void k2b_dvec(
    const float* __restrict__ bq, const float* __restrict__ bk,
    const float* __restrict__ We, const float* __restrict__ be,
    float* __restrict__ dvec) {
  __shared__ float part[16][32];
  const int tid = threadIdx.x;  // 512
  const int j = tid & 31, p = tid >> 5;  // p 0..15
  const int mat = j >> 4, col = j & 15;
  const float* b = mat ? bk : bq;
  float acc = 0.f;
  for (int n = p * 64; n < p * 64 + 64; ++n) acc += b[n] * We[n * QD + col];
  part[p][j] = acc;
  __syncthreads();
  if (tid < 32) {
    float sum = be[tid & 15];
    for (int p2 = 0; p2 < 16; ++p2) sum += part[p2][tid];
    dvec[tid] = sum;
  }
}

// ---------------- embed via MFMA (hi/lo split), fused normalize ----------------
// v2: 1024 threads, 4-way K-split (each 256-thread group owns a K quarter),
// 4 staging rounds instead of 16, 4 waves/SIMD instead of 1. Partial
// accumulators combined via LDS at the end. Outputs bf16 qq/kk in [S][32]
// layout, zero-padded upper half; qq carries sqrt(log2 e).
__global__ __launch_bounds__(1024) void k3_embed_mfma(
    const __bf16* __restrict__ xh, const __bf16* __restrict__ xl,
    const __bf16* __restrict__ Cth, const __bf16* __restrict__ Ctl,
    const float* __restrict__ dvec, __bf16* __restrict__ qq32,
    __bf16* __restrict__ kk32) {
  __shared__ __bf16 Ah[4][32 * 64];
  __shared__ __bf16 Al[4][32 * 64];
  __shared__ __bf16 Bh[4][32 * 64];
  __shared__ __bf16 Bl[4][32 * 64];
  const int tid = threadIdx.x;
  const int lane = tid & 63;
  const int w = tid >> 6;       // 0..15
  const int kb = w >> 2;        // K quarter this wave computes on
  const int w4 = w & 3;
  const int rowhalf = w4 >> 1;  // 0/1 -> rows 0-15 / 16-31
  const int ntile = w4 & 1;     // 0 -> qq, 1 -> kk
  const int l15 = lane & 15, quad = lane >> 4;
  const long rowBase = (long)blockIdx.x * 32;

  // staging: 256-thread group `half` stages K range [half*256, half*256+256)
  const int half = tid >> 8;       // 0..3
  const int tl = tid & 255;
  const int srow = tl >> 3;        // 0..31
  const int seg = tl & 7;
  const int segsw = (seg ^ (srow & 7)) * 8;
  const long gk = half * 256 + segsw;
  const __bf16* agh = xh + (rowBase + srow) * H + gk;
  const __bf16* agl = xl + (rowBase + srow) * H + gk;
  const __bf16* bgh = Cth + (long)srow * H + gk;
  const __bf16* bgl = Ctl + (long)srow * H + gk;
  __bf16* lah = &Ah[half][srow * 64 + seg * 8];
  __bf16* lal = &Al[half][srow * 64 + seg * 8];
  __bf16* lbh = &Bh[half][srow * 64 + seg * 8];
  __bf16* lbl = &Bl[half][srow * 64 + seg * 8];

  f32x4 acc;
  acc[0] = 0.f; acc[1] = 0.f; acc[2] = 0.f; acc[3] = 0.f;
  const int arow = (rowhalf * 16 + l15) * 64;
  const int brow = (ntile * 16 + l15) * 64;
  const int h7 = l15 & 7;

  for (int k0 = 0; k0 < 256; k0 += 64) {
    async_g2l_16(agh + k0, lah);
    async_g2l_16(agl + k0, lal);
    async_g2l_16(bgh + k0, lbh);
    async_g2l_16(bgl + k0, lbl);
    __syncthreads();
#pragma unroll
    for (int s = 0; s < 2; ++s) {
      const int slot = ((s * 4 + quad) ^ h7) * 8;
      bf16x8 fah = *(const bf16x8*)&Ah[kb][arow + slot];
      bf16x8 fal = *(const bf16x8*)&Al[kb][arow + slot];
      bf16x8 fbh = *(const bf16x8*)&Bh[kb][brow + slot];
      bf16x8 fbl = *(const bf16x8*)&Bl[kb][brow + slot];
      acc = __builtin_amdgcn_mfma_f32_16x16x32_bf16(fah, fbh, acc, 0, 0, 0);
      acc = __builtin_amdgcn_mfma_f32_16x16x32_bf16(fal, fbh, acc, 0, 0, 0);
      acc = __builtin_amdgcn_mfma_f32_16x16x32_bf16(fah, fbl, acc, 0, 0, 0);
    }
    __syncthreads();
  }

  // combine the 4 K-quarter partials: waves kb>0 dump to LDS, kb==0 sums.
  if (kb > 0) ((f32x4*)&Ah[kb][0])[w4 * 64 + lane] = acc;
  __syncthreads();
  if (kb == 0) {
#pragma unroll
    for (int q = 1; q < 4; ++q) {
      f32x4 o = ((const f32x4*)&Ah[q][0])[w4 * 64 + lane];
      acc[0] += o[0]; acc[1] += o[1]; acc[2] += o[2]; acc[3] += o[3];
    }
    const float dv = dvec[ntile * 16 + l15];
    // fold sqrt(log2 e) into qq so S^2 arrives pre-scaled for exp2
    const float osc = ntile ? 1.0f : 1.20112240878f;
    __bf16* outp = ntile ? kk32 : qq32;
#pragma unroll
    for (int r = 0; r < 4; ++r) {
      float z = acc[r] + dv;
      float s2 = z * z;
      s2 += __shfl_xor(s2, 1);
      s2 += __shfl_xor(s2, 2);
      s2 += __shfl_xor(s2, 4);
      s2 += __shfl_xor(s2, 8);
      float val = z * rsqrtf(s2 + 1e-8f) * osc;
      long row = rowBase + rowhalf * 16 + quad * 4 + r;
      outp[row * 32 + l15] = (__bf16)val;
      outp[row * 32 + 16 + l15] = (__bf16)0.f;  // zero pad K 16->32
    }
  }
}

// ---------------- fused attention, 8 waves, 128q x 256h tile ----------------
// R3 pipeline (verified 54us) + R5's XCD-aware remap (verified FETCH 70->9MB):
// KCH=64, V TRIPLE-buffered (3x32KB) via global_load_lds w/ pre-swizzled
// source, P DOUBLE-buffered (16B-granule XOR swizzle). ONE s_barrier per
// chunk, counted s_waitcnt vmcnt(6). Buffer safety: stage(t)->buf (t+1)%3;
// PV(t) reads buf t%3; P halves alternate; fast waves blocked by barrier(t+1).
__global__ __launch_bounds__(512) void fused_attn(
    const __bf16* __restrict__ qq32, const __bf16* __restrict__ kk32,
    const __bf16* __restrict__ v_t, __bf16* __restrict__ attn) {
  __shared__ __bf16 Vlds[3][256 * KCH];  // 96KB
  __shared__ __bf16 Plds[2][128 * KCH];  // 32KB
  __shared__ float rsum2[128 * 2];
  const int tid = threadIdx.x;
  const int lane = tid & 63;
  const int w = tid >> 6;  // 0..7
  const int l15 = lane & 15, quad = lane >> 4;
  const int ws_k = w & 1, ws_q = w >> 1;  // S-phase roles
  const int wp_h = w & 3, wp_q = w >> 2;  // PV-phase roles

  // XCD-aware remap: 256 blocks, 8 XCDs, 16 (b,h) panels -> 2 panels/XCD;
  // all 16 q-blocks of a panel land on the same XCD (1MB V panel L2-resident).
  const int bid = blockIdx.x;             // 0..255
  const int xcd = bid & 7, s = bid >> 3;  // s: 0..31
  const int panel = xcd * 2 + (s >> 4);   // 0..15
  const int b = panel >> 2;
  const long hbase = (long)(panel & 3) * 256;
  const long qbase = (long)(s & 15) * 128;

  // qq B-frags: 2, constant across the k-loop
  bf16x8 bq[2];
  {
    const __bf16* qqp =
        qq32 + ((long)b * SEQ + qbase + ws_q * 32 + l15) * 32 + quad * 8;
    bq[0] = *(const bf16x8*)qqp;
    bq[1] = *(const bf16x8*)(qqp + 16 * 32);
  }
  const __bf16* kkb = kk32 + ((long)b * SEQ + ws_k * 32 + l15) * 32 + quad * 8;

  // V staging: linear LDS dest (tid*16B), pre-swizzled global source.
  const int vR = tid >> 3;               // 0..63
  const int vSL = (tid & 7) ^ (vR & 7);  // swizzled global 16B-granule
  const __bf16* vgbase = v_t + (long)b * H * SEQ + (hbase + vR) * SEQ + vSL * 8;

  f32x4 acc[4][4];
#pragma unroll
  for (int i = 0; i < 4; ++i)
#pragma unroll
    for (int j = 0; j < 4; ++j) {
      acc[i][j][0] = 0.f; acc[i][j][1] = 0.f; acc[i][j][2] = 0.f; acc[i][j][3] = 0.f;
    }
  float rsPart[2] = {0.f, 0.f};

  // prologue: stage chunk 0 -> buf0 (4 vmem), load kk frags chunk 0 (2 vmem)
#pragma unroll
  for (int j = 0; j < 4; ++j)
    async_g2l_16(vgbase + (long)j * 64 * SEQ, &Vlds[0][j * 64 * KCH + tid * 8]);
  bf16x8 ak[2];
  ak[0] = *(const bf16x8*)kkb;
  ak[1] = *(const bf16x8*)(kkb + 16 * 32);

  int vcur = 0, vnxt = 1;
  for (int t = 0; t < SEQ / KCH; ++t) {
    const int kn = ((t + 1) & (SEQ / KCH - 1)) * KCH;  // wraps (dummy) at last
    // 1) issue stage of chunk t+1 (4 vmem ops)
#pragma unroll
    for (int j = 0; j < 4; ++j)
      async_g2l_16(vgbase + (long)j * 64 * SEQ + kn,
                   &Vlds[vnxt][j * 64 * KCH + tid * 8]);

    // 2) S-phase (chunk t): 4 MFMAs from regs -> exp2 -> Plds[t&1]
    __bf16* Pw = Plds[t & 1];
#pragma unroll
    for (int i = 0; i < 2; ++i) {
#pragma unroll
      for (int n = 0; n < 2; ++n) {
        f32x4 s2v;
        s2v[0] = 0.f; s2v[1] = 0.f; s2v[2] = 0.f; s2v[3] = 0.f;
        s2v = __builtin_amdgcn_mfma_f32_16x16x32_bf16(ak[i], bq[n], s2v, 0, 0, 0);
        bf16x4 pw;
        float part = 0.f;
#pragma unroll
        for (int r = 0; r < 4; ++r) {
          float wgt = exp2f(s2v[r] * s2v[r]);  // qq carries sqrt(log2e)
          part += wgt;
          pw[r] = (__bf16)wgt;
        }
        rsPart[n] += part;
        const int q = ws_q * 32 + n * 16 + l15;
        const int g = ws_k * 4 + i * 2 + (quad >> 1);
        *(bf16x4*)&Pw[q * KCH + ((g ^ (q & 7)) << 3) + (quad & 1) * 4] = pw;
      }
    }
    // 3) prefetch kk frags for chunk t+1 (2 vmem ops)
    ak[0] = *(const bf16x8*)(kkb + (long)kn * 32);
    ak[1] = *(const bf16x8*)(kkb + (long)(kn + 16) * 32);

    // 4) P writes visible; chunk-t V staged (6 younger vmem stay in flight)
    asm volatile("s_waitcnt lgkmcnt(0)" ::: "memory");
    asm volatile("s_waitcnt vmcnt(6)" ::: "memory");
    __builtin_amdgcn_sched_barrier(0);
    __builtin_amdgcn_s_barrier();

    // 5) PV: acc += P[128q x 64k] @ V[256h x 64k]^T   (wave: 64q x 64h)
    const __bf16* Vr = Vlds[vcur];
#pragma unroll
    for (int ks = 0; ks < 2; ++ks) {
      bf16x8 ap[4], bv[4];
#pragma unroll
      for (int i = 0; i < 4; ++i) {
        const int q = wp_q * 64 + i * 16 + l15;
        ap[i] = *(const bf16x8*)&Pw[q * KCH + (((ks * 4 + quad) ^ (q & 7)) << 3)];
      }
#pragma unroll
      for (int j = 0; j < 4; ++j) {
        const int vr = wp_h * 64 + j * 16 + l15;
        bv[j] = *(const bf16x8*)&Vr[vr * KCH + (((ks * 4 + quad) ^ (vr & 7)) << 3)];
      }
#pragma unroll
      for (int i = 0; i < 4; ++i)
#pragma unroll
        for (int j = 0; j < 4; ++j)
          acc[i][j] =
              __builtin_amdgcn_mfma_f32_16x16x32_bf16(ap[i], bv[j], acc[i][j], 0, 0, 0);
    }
    // 6) rotate V buffers (no second barrier needed: see header comment)
    const int third = 3 - vcur - vnxt;
    vcur = vnxt;
    vnxt = third;
  }

  // rowsum: reduce lane partials over quads, combine two k-halves via LDS
#pragma unroll
  for (int n = 0; n < 2; ++n) {
    float vs = rsPart[n];
    vs += __shfl_xor(vs, 16);
    vs += __shfl_xor(vs, 32);
    if (lane < 16) rsum2[(ws_q * 32 + n * 16 + l15) * 2 + ws_k] = vs;
  }
  __syncthreads();  // also drains the final dummy stage

  float rinv[4][4];
#pragma unroll
  for (int i = 0; i < 4; ++i)
#pragma unroll
    for (int r = 0; r < 4; ++r) {
      int row = wp_q * 64 + i * 16 + quad * 4 + r;
      rinv[i][r] = 1.0f / (rsum2[row * 2] + rsum2[row * 2 + 1]);
    }

  __bf16* ob = attn + ((long)b * SEQ + qbase) * H + hbase;
#pragma unroll
  for (int i = 0; i < 4; ++i)
#pragma unroll
    for (int j = 0; j < 4; ++j) {
      const int colL = wp_h * 64 + j * 16 + l15;
#pragma unroll
      for (int r = 0; r < 4; ++r) {
        const int rowL = wp_q * 64 + i * 16 + quad * 4 + r;
        ob[(long)rowL * H + colL] = (__bf16)(acc[i][j][r] * rinv[i][r]);
      }
    }
}

// ---------------- m97-style GEMM + XOR-swizzled LDS: C = A @ Bt^T (+bias) ----
// OUTMODE: 0 = fp32 row-major, 1 = bf16 row-major, 2 = bf16 transposed batched
//          (Cout layout [BATCH][N][SEQ], rows are per-batch: row = b*SEQ + rb)
template <int OUTMODE, int HASBIAS>
__global__ __launch_bounds__(256) void gemm_bt(
    const __bf16* __restrict__ A, const __bf16* __restrict__ Bt,
    void* __restrict__ Cout, const float* __restrict__ bias, int M, int N, int K) {
  __shared__ __bf16 Alds[128 * 64];
  __shared__ __bf16 Blds[128 * 64];
  const int tid = threadIdx.x;
  const int lane = tid & 63;
  const int w = tid >> 6;
  const int wm = w >> 1, wn = w & 1;
  const int l15 = lane & 15, quad = lane >> 4;
  const long rowBase = (long)blockIdx.y * 128;
  const long colBase = (long)blockIdx.x * 128;

  const int srow = lane >> 3;                 // 0..7
  const int segsw = ((lane & 7) ^ srow) * 8;  // swizzled global k-seg

  const __bf16* ag[4];
  const __bf16* bg[4];
  __bf16* as_[4];
  __bf16* bs_[4];
#pragma unroll
  for (int j = 0; j < 4; ++j) {
    int r = j * 32 + w * 8;
    ag[j] = A + (rowBase + r + srow) * (long)K + segsw;
    bg[j] = Bt + (colBase + r + srow) * (long)K + segsw;
    as_[j] = &Alds[r * 64 + (lane & 7) * 8];
    bs_[j] = &Blds[r * 64 + (lane & 7) * 8];
  }

  f32x4 acc[4][4];
#pragma unroll
  for (int i = 0; i < 4; ++i)
#pragma unroll
    for (int j = 0; j < 4; ++j) {
      acc[i][j][0] = 0.f; acc[i][j][1] = 0.f; acc[i][j][2] = 0.f; acc[i][j][3] = 0.f;
    }

  const int h7 = l15 & 7;

  for (int k0 = 0; k0 < K; k0 += 64) {
#pragma unroll
    for (int j = 0; j < 4; ++j) {
      async_g2l_16(ag[j], as_[j]);
      async_g2l_16(bg[j], bs_[j]);
      ag[j] += 64;
      bg[j] += 64;
    }
    __syncthreads();
#pragma unroll
    for (int s = 0; s < 2; ++s) {
      const int slot = ((s * 4 + quad) ^ h7) * 8;
      bf16x8 af[4], bfv[4];
#pragma unroll
      for (int i = 0; i < 4; ++i) {
        af[i] = *(const bf16x8*)&Alds[(wm * 64 + i * 16 + l15) * 64 + slot];
        bfv[i] = *(const bf16x8*)&Blds[(wn * 64 + i * 16 + l15) * 64 + slot];
      }
#pragma unroll
      for (int i = 0; i < 4; ++i)
#pragma unroll
        for (int j = 0; j < 4; ++j)
          acc[i][j] =
              __builtin_amdgcn_mfma_f32_16x16x32_bf16(af[i], bfv[j], acc[i][j], 0, 0, 0);
    }
    __syncthreads();
  }

  const long crow0 = rowBase + wm * 64 + quad * 4;
  const long ccol0 = colBase + wn * 64 + l15;
#pragma unroll
  for (int i = 0; i < 4; ++i) {
#pragma unroll
    for (int j = 0; j < 4; ++j) {
      long col = ccol0 + j * 16;
      float bb = HASBIAS ? bias[col] : 0.f;
      if (OUTMODE == 2) {
        long row0 = crow0 + i * 16;          // 4 consecutive rows, same batch
        int bz = (int)(row0 >> 11);          // row / SEQ
        long rb = row0 & (SEQ - 1);
        bf16x4 pv;
#pragma unroll
        for (int r = 0; r < 4; ++r) pv[r] = (__bf16)(acc[i][j][r] + bb);
        *(bf16x4*)&((__bf16*)Cout)[((long)bz * N + col) * SEQ + rb] = pv;
      } else {
#pragma unroll
        for (int r = 0; r < 4; ++r) {
          long row = crow0 + i * 16 + r;
          float val = acc[i][j][r] + bb;
          if (OUTMODE == 0)
            ((float*)Cout)[row * N + col] = val;
          else
            ((__bf16*)Cout)[row * N + col] = (__bf16)val;
        }
      }
    }
  }
}

extern "C" void kernel_launch(void* const* d_in, const int* in_sizes, int n_in,
                              void* d_out, int out_size, void* d_ws, size_t ws_size,
                              hipStream_t stream) {
  const float* x = (const float*)d_in[0];
  const float* Wq = (const float*)d_in[1];
  const float* bq = (const float*)d_in[2];
  const float* Wk = (const float*)d_in[3];
  const float* bk = (const float*)d_in[4];
  const float* Wv = (const float*)d_in[5];
  const float* bv = (const float*)d_in[6];
  const float* We = (const float*)d_in[7];
  const float* be = (const float*)d_in[8];
  const float* Wo = (const float*)d_in[9];
  const float* bo = (const float*)d_in[10];
  float* out = (float*)d_out;

  char* ws = (char*)d_ws;
  size_t o = 0;
  auto alloc = [&](size_t n) {
    size_t r = o;
    o += (n + 255) & ~(size_t)255;
    return r;
  };
  __bf16* xbf = (__bf16*)(ws + alloc((size_t)MROWS * H * 2));  // x hi
  __bf16* v_t = (__bf16*)(ws + alloc((size_t)MROWS * H * 2));  // v^T [B][H][S]
  __bf16* attn = (__bf16*)(ws + alloc((size_t)MROWS * H * 2));
  __bf16* Wvt = (__bf16*)(ws + alloc((size_t)H * H * 2));
  __bf16* Wot = (__bf16*)(ws + alloc((size_t)H * H * 2));
  __bf16* Cth = (__bf16*)(ws + alloc((size_t)32 * H * 2));
  __bf16* Ctl = (__bf16*)(ws + alloc((size_t)32 * H * 2));
  float* dvec = (float*)(ws + alloc(32 * 4));
  __bf16* qq32 = (__bf16*)(ws + alloc((size_t)MROWS * 32 * 2));
  __bf16* kk32 = (__bf16*)(ws + alloc((size_t)MROWS * 32 * 2));
  // Alias (stream-ordered lifetime separation):
  __bf16* xlo = attn;  // x lo part: dead before attn is written (fused_attn)
  if (ws_size < o) return;

  // 1) x -> bf16 hi/lo split
  cvt_split<<<MROWS * H / 1024, 256, 0, stream>>>(x, xbf, xlo, MROWS * H);
  // 2) Wv^T, Wo^T as bf16
  transpose_cvt_f32_bf16<<<dim3(32, 32), 256, 0, stream>>>(Wv, Wvt, H, H);
  transpose_cvt_f32_bf16<<<dim3(32, 32), 256, 0, stream>>>(Wo, Wot, H, H);
  // 3) collapsed embed matrices (bf16 hi/lo, Bt layout) + bias fold
  k2_cqk<<<512, 256, 0, stream>>>(Wq, Wk, We, Cth, Ctl);
  k2b_dvec<<<1, 512, 0, stream>>>(bq, bk, We, be, dvec);
  // 4) unit-norm quantum embeds via MFMA (4-way K-split, 16 waves)
  k3_embed_mfma<<<MROWS / 32, 1024, 0, stream>>>(xbf, xlo, Cth, Ctl, dvec, qq32, kk32);
  // 5) v = x@Wv + bv, written TRANSPOSED per batch -> v_t[b][h][s]
  gemm_bt<2, 1><<<dim3(8, 64), 256, 0, stream>>>(xbf, Wvt, v_t, bv, MROWS, H, H);
  // 6) fused: S^T once per 256h -> exp2(S'^2) -> P@v/rowsum  (bf16 out)
  fused_attn<<<256, 512, 0, stream>>>(qq32, kk32, v_t, attn);
  // 7) out = attended @ Wo + bo  (fp32 out)
  gemm_bt<0, 1><<<dim3(8, 64), 256, 0, stream>>>(attn, Wot, out, bo, MROWS, H, H);
}

// Round 7
// 235.077 us; speedup vs baseline: 1.1779x; 1.0230x over previous
//
#include <hip/hip_runtime.h>

#define H 1024
#define QD 16
#define BATCH 4
#define SEQ 2048
#define MROWS 8192  // BATCH*SEQ
#define KCH 64      // fused_attn k-chunk

typedef __bf16 bf16x8 __attribute__((ext_vector_type(8)));
typedef __bf16 bf16x4 __attribute__((ext_vector_type(4)));
typedef float f32x4 __attribute__((ext_vector_type(4)));

__device__ __forceinline__ void async_g2l_16(const void* g, void* l) {
  __builtin_amdgcn_global_load_lds(
      (const __attribute__((address_space(1))) unsigned int*)g,
      (__attribute__((address_space(3))) unsigned int*)l, 16, 0, 0);
}

// ---------------- fp32 -> bf16 hi/lo split (x) ----------------
__global__ __launch_bounds__(256) void cvt_split(const float* __restrict__ src,
                                                 __bf16* __restrict__ hi,
                                                 __bf16* __restrict__ lo, int n) {
  int i = (blockIdx.x * 256 + threadIdx.x) * 4;
  if (i < n) {
    float4 f = *(const float4*)(src + i);
    bf16x4 h, l;
    h[0] = (__bf16)f.x; l[0] = (__bf16)(f.x - (float)h[0]);
    h[1] = (__bf16)f.y; l[1] = (__bf16)(f.y - (float)h[1]);
    h[2] = (__bf16)f.z; l[2] = (__bf16)(f.z - (float)h[2]);
    h[3] = (__bf16)f.w; l[3] = (__bf16)(f.w - (float)h[3]);
    *(bf16x4*)(hi + i) = h;
    *(bf16x4*)(lo + i) = l;
  }
}

// ---------------- fp32 [R][C] -> bf16 transposed [C][R] ----------------
__global__ __launch_bounds__(256) void transpose_cvt_f32_bf16(
    const float* __restrict__ src, __bf16* __restrict__ dst, int R, int C) {
  __shared__ float t[32][33];
  const int rb = blockIdx.y * 32, cb = blockIdx.x * 32;
  const int c = threadIdx.x & 31;
  const int r0 = threadIdx.x >> 5;
#pragma unroll
  for (int rr = r0; rr < 32; rr += 8)
    t[rr][c] = src[(long)(rb + rr) * C + cb + c];
  __syncthreads();
#pragma unroll
  for (int rr = r0; rr < 32; rr += 8)
    dst[(long)(cb + rr) * R + rb + c] = (__bf16)t[c][rr];
}

// ---------------- CqkT (Bt layout [32][1024]) in bf16 hi/lo ----------------
// v2: float4 W reads (4x fewer W load instrs); We stays scalar (L1-hot 64KB).
__global__ __launch_bounds__(256) void k2_cqk(const float* __restrict__ Wq,
                                              const float* __restrict__ Wk,
                                              const float* __restrict__ We,
                                              __bf16* __restrict__ Cth,
                                              __bf16* __restrict__ Ctl) {
  const int gw = blockIdx.x * 4 + (threadIdx.x >> 6);  // 0..2047
  const int lane = threadIdx.x & 63;
  const int mat = gw & 1, k = gw >> 1;
  const float* Wrow = (mat ? Wk : Wq) + (long)k * H;
  const int col = lane & 15, q4 = lane >> 4;
  const float* wp = Wrow + q4 * 256;
  const float* wep = We + (long)q4 * 256 * QD + col;
  float acc = 0.f;
#pragma unroll 4
  for (int n0 = 0; n0 < 256; n0 += 4) {
    float4 w4 = *(const float4*)(wp + n0);
    acc += w4.x * wep[(n0 + 0) * QD];
    acc += w4.y * wep[(n0 + 1) * QD];
    acc += w4.z * wep[(n0 + 2) * QD];
    acc += w4.w * wep[(n0 + 3) * QD];
  }
  acc += __shfl_xor(acc, 16);
  acc += __shfl_xor(acc, 32);
  if (lane < 16) {
    __bf16 hi = (__bf16)acc;
    __bf16 lo = (__bf16)(acc - (float)hi);
    long idx = (long)(mat * 16 + col) * H + k;
    Cth[idx] = hi;
    Ctl[idx] = lo;
  }
}

// ---------------- dvec[j] = (bq|bk)@We + be (parallel v2) ----------------
__global__ __launch_bounds__(512) void k2b_dvec(
    const float* __restrict__ bq, const float* __restrict__ bk,
    const float* __restrict__ We, const float* __restrict__ be,
    float* __restrict__ dvec) {
  __shared__ float part[16][32];
  const int tid = threadIdx.x;  // 512
  const int j = tid & 31, p = tid >> 5;  // p 0..15
  const int mat = j >> 4, col = j & 15;
  const float* b = mat ? bk : bq;
  float acc = 0.f;
  for (int n = p * 64; n < p * 64 + 64; ++n) acc += b[n] * We[n * QD + col];
  part[p][j] = acc;
  __syncthreads();
  if (tid < 32) {
    float sum = be[tid & 15];
    for (int p2 = 0; p2 < 16; ++p2) sum += part[p2][tid];
    dvec[tid] = sum;
  }
}

// ---------------- embed via MFMA (hi/lo split), fused normalize ----------------
// v2: 1024 threads, 4-way K-split (each 256-thread group owns a K quarter),
// 4 staging rounds instead of 16, 4 waves/SIMD instead of 1. Partial
// accumulators combined via LDS at the end. Outputs bf16 qq/kk in [S][32]
// layout, zero-padded upper half; qq carries sqrt(log2 e).
__global__ __launch_bounds__(1024) void k3_embed_mfma(
    const __bf16* __restrict__ xh, const __bf16* __restrict__ xl,
    const __bf16* __restrict__ Cth, const __bf16* __restrict__ Ctl,
    const float* __restrict__ dvec, __bf16* __restrict__ qq32,
    __bf16* __restrict__ kk32) {
  __shared__ __bf16 Ah[4][32 * 64];
  __shared__ __bf16 Al[4][32 * 64];
  __shared__ __bf16 Bh[4][32 * 64];
  __shared__ __bf16 Bl[4][32 * 64];
  const int tid = threadIdx.x;
  const int lane = tid & 63;
  const int w = tid >> 6;       // 0..15
  const int kb = w >> 2;        // K quarter this wave computes on
  const int w4 = w & 3;
  const int rowhalf = w4 >> 1;  // 0/1 -> rows 0-15 / 16-31
  const int ntile = w4 & 1;     // 0 -> qq, 1 -> kk
  const int l15 = lane & 15, quad = lane >> 4;
  const long rowBase = (long)blockIdx.x * 32;

  // staging: 256-thread group `half` stages K range [half*256, half*256+256)
  const int half = tid >> 8;       // 0..3
  const int tl = tid & 255;
  const int srow = tl >> 3;        // 0..31
  const int seg = tl & 7;
  const int segsw = (seg ^ (srow & 7)) * 8;
  const long gk = half * 256 + segsw;
  const __bf16* agh = xh + (rowBase + srow) * H + gk;
  const __bf16* agl = xl + (rowBase + srow) * H + gk;
  const __bf16* bgh = Cth + (long)srow * H + gk;
  const __bf16* bgl = Ctl + (long)srow * H + gk;
  __bf16* lah = &Ah[half][srow * 64 + seg * 8];
  __bf16* lal = &Al[half][srow * 64 + seg * 8];
  __bf16* lbh = &Bh[half][srow * 64 + seg * 8];
  __bf16* lbl = &Bl[half][srow * 64 + seg * 8];

  f32x4 acc;
  acc[0] = 0.f; acc[1] = 0.f; acc[2] = 0.f; acc[3] = 0.f;
  const int arow = (rowhalf * 16 + l15) * 64;
  const int brow = (ntile * 16 + l15) * 64;
  const int h7 = l15 & 7;

  for (int k0 = 0; k0 < 256; k0 += 64) {
    async_g2l_16(agh + k0, lah);
    async_g2l_16(agl + k0, lal);
    async_g2l_16(bgh + k0, lbh);
    async_g2l_16(bgl + k0, lbl);
    __syncthreads();
#pragma unroll
    for (int s = 0; s < 2; ++s) {
      const int slot = ((s * 4 + quad) ^ h7) * 8;
      bf16x8 fah = *(const bf16x8*)&Ah[kb][arow + slot];
      bf16x8 fal = *(const bf16x8*)&Al[kb][arow + slot];
      bf16x8 fbh = *(const bf16x8*)&Bh[kb][brow + slot];
      bf16x8 fbl = *(const bf16x8*)&Bl[kb][brow + slot];
      acc = __builtin_amdgcn_mfma_f32_16x16x32_bf16(fah, fbh, acc, 0, 0, 0);
      acc = __builtin_amdgcn_mfma_f32_16x16x32_bf16(fal, fbh, acc, 0, 0, 0);
      acc = __builtin_amdgcn_mfma_f32_16x16x32_bf16(fah, fbl, acc, 0, 0, 0);
    }
    __syncthreads();
  }

  // combine the 4 K-quarter partials: waves kb>0 dump to LDS, kb==0 sums.
  if (kb > 0) ((f32x4*)&Ah[kb][0])[w4 * 64 + lane] = acc;
  __syncthreads();
  if (kb == 0) {
#pragma unroll
    for (int q = 1; q < 4; ++q) {
      f32x4 o = ((const f32x4*)&Ah[q][0])[w4 * 64 + lane];
      acc[0] += o[0]; acc[1] += o[1]; acc[2] += o[2]; acc[3] += o[3];
    }
    const float dv = dvec[ntile * 16 + l15];
    // fold sqrt(log2 e) into qq so S^2 arrives pre-scaled for exp2
    const float osc = ntile ? 1.0f : 1.20112240878f;
    __bf16* outp = ntile ? kk32 : qq32;
#pragma unroll
    for (int r = 0; r < 4; ++r) {
      float z = acc[r] + dv;
      float s2 = z * z;
      s2 += __shfl_xor(s2, 1);
      s2 += __shfl_xor(s2, 2);
      s2 += __shfl_xor(s2, 4);
      s2 += __shfl_xor(s2, 8);
      float val = z * rsqrtf(s2 + 1e-8f) * osc;
      long row = rowBase + rowhalf * 16 + quad * 4 + r;
      outp[row * 32 + l15] = (__bf16)val;
      outp[row * 32 + 16 + l15] = (__bf16)0.f;  // zero pad K 16->32
    }
  }
}

// ---------------- fused attention, 16 waves, 128q x 256h tile ----------------
// v2: 1024 threads (4 waves/SIMD, was 2) — same tile, same LDS (129KB), same
// verified triple-buffer/one-barrier/counted-vmcnt pipeline as R3/R6.
// S-phase: 16 waves = 8 q-slots(16) x 2 k-halves(32): 2 MFMA + 8 exps/wave.
// PV-phase: 16 waves = 4 q-quarters(32) x 4 h-quarters(64): 16 MFMA/wave.
// Buffer safety: stage(t)->buf (t+1)%3; PV(t) reads buf t%3; skew <=1 barrier
// so laggard readers at t and fast stagers at t+2 never collide ((t+2)%3!=t%3);
// P halves alternate. vmcnt(4) = 2 stage(t+1) + 2 kk(t+1) younger at the wait.
__global__ __launch_bounds__(1024) void fused_attn(
    const __bf16* __restrict__ qq32, const __bf16* __restrict__ kk32,
    const __bf16* __restrict__ v_t, __bf16* __restrict__ attn) {
  __shared__ __bf16 Vlds[3][256 * KCH];  // 96KB
  __shared__ __bf16 Plds[2][128 * KCH];  // 32KB
  __shared__ float rsum2[128 * 2];
  const int tid = threadIdx.x;
  const int lane = tid & 63;
  const int w = tid >> 6;  // 0..15
  const int l15 = lane & 15, quad = lane >> 4;
  const int sq = w >> 1, sk = w & 1;      // S-phase roles: 8q-slots x 2k-halves
  const int wp_h = w & 3, wp_q = w >> 2;  // PV-phase roles: 4h x 4q

  // XCD-aware remap: 256 blocks, 8 XCDs, 16 (b,h) panels -> 2 panels/XCD;
  // all 16 q-blocks of a panel land on the same XCD (1MB V panel L2-resident).
  const int bid = blockIdx.x;             // 0..255
  const int xcd = bid & 7, s = bid >> 3;  // s: 0..31
  const int panel = xcd * 2 + (s >> 4);   // 0..15
  const int b = panel >> 2;
  const long hbase = (long)(panel & 3) * 256;
  const long qbase = (long)(s & 15) * 128;

  // qq B-frag (16 q rows), constant across the k-loop
  const bf16x8 bq = *(const bf16x8*)(qq32 +
      ((long)b * SEQ + qbase + sq * 16 + l15) * 32 + quad * 8);
  const __bf16* kkb = kk32 + ((long)b * SEQ + sk * 32 + l15) * 32 + quad * 8;

  // V staging: 32KB chunk = 2048 granules, 2 per thread (rows vR, vR+128).
  // LDS dest is wave-lane-linear (base + lane*16B); global source pre-swizzled.
  const int vR = tid >> 3;               // 0..127
  const int vSL = (tid & 7) ^ (vR & 7);  // swizzled global 16B-granule
  const __bf16* vg0 = v_t + (long)b * H * SEQ + (hbase + vR) * SEQ + vSL * 8;
  const __bf16* vg1 = vg0 + (long)128 * SEQ;  // (vR+128)&7 == vR&7: same swizzle

  f32x4 acc[2][4];
#pragma unroll
  for (int i = 0; i < 2; ++i)
#pragma unroll
    for (int j = 0; j < 4; ++j) {
      acc[i][j][0] = 0.f; acc[i][j][1] = 0.f; acc[i][j][2] = 0.f; acc[i][j][3] = 0.f;
    }
  float rsPart = 0.f;

  // prologue: stage chunk 0 -> buf0 (2 vmem), load kk frags chunk 0 (2 vmem)
  async_g2l_16(vg0, &Vlds[0][vR * KCH + (tid & 7) * 8]);
  async_g2l_16(vg1, &Vlds[0][(vR + 128) * KCH + (tid & 7) * 8]);
  bf16x8 ak[2];
  ak[0] = *(const bf16x8*)kkb;
  ak[1] = *(const bf16x8*)(kkb + 16 * 32);

  int vcur = 0, vnxt = 1;
  for (int t = 0; t < SEQ / KCH; ++t) {
    const int kn = ((t + 1) & (SEQ / KCH - 1)) * KCH;  // wraps (dummy) at last
    // 1) issue stage of chunk t+1 (2 vmem ops)
    async_g2l_16(vg0 + kn, &Vlds[vnxt][vR * KCH + (tid & 7) * 8]);
    async_g2l_16(vg1 + kn, &Vlds[vnxt][(vR + 128) * KCH + (tid & 7) * 8]);

    // 2) S-phase (chunk t): 2 MFMAs -> exp2 -> Plds[t&1]
    __bf16* Pw = Plds[t & 1];
#pragma unroll
    for (int i = 0; i < 2; ++i) {
      f32x4 s2v;
      s2v[0] = 0.f; s2v[1] = 0.f; s2v[2] = 0.f; s2v[3] = 0.f;
      s2v = __builtin_amdgcn_mfma_f32_16x16x32_bf16(ak[i], bq, s2v, 0, 0, 0);
      bf16x4 pw;
      float part = 0.f;
#pragma unroll
      for (int r = 0; r < 4; ++r) {
        float wgt = exp2f(s2v[r] * s2v[r]);  // qq carries sqrt(log2e)
        part += wgt;
        pw[r] = (__bf16)wgt;
      }
      rsPart += part;
      const int q = sq * 16 + l15;
      const int g = sk * 4 + i * 2 + (quad >> 1);
      *(bf16x4*)&Pw[q * KCH + ((g ^ (q & 7)) << 3) + (quad & 1) * 4] = pw;
    }
    // 3) prefetch kk frags for chunk t+1 (2 vmem ops)
    ak[0] = *(const bf16x8*)(kkb + (long)kn * 32);
    ak[1] = *(const bf16x8*)(kkb + (long)(kn + 16) * 32);

    // 4) P writes visible; chunk-t V staged (4 younger vmem stay in flight)
    asm volatile("s_waitcnt lgkmcnt(0)" ::: "memory");
    asm volatile("s_waitcnt vmcnt(4)" ::: "memory");
    __builtin_amdgcn_sched_barrier(0);
    __builtin_amdgcn_s_barrier();

    // 5) PV: acc += P[128q x 64k] @ V[256h x 64k]^T   (wave: 32q x 64h)
    const __bf16* Vr = Vlds[vcur];
#pragma unroll
    for (int ks = 0; ks < 2; ++ks) {
      bf16x8 ap[2], bv[4];
#pragma unroll
      for (int i = 0; i < 2; ++i) {
        const int q = wp_q * 32 + i * 16 + l15;
        ap[i] = *(const bf16x8*)&Pw[q * KCH + (((ks * 4 + quad) ^ (q & 7)) << 3)];
      }
#pragma unroll
      for (int j = 0; j < 4; ++j) {
        const int vr = wp_h * 64 + j * 16 + l15;
        bv[j] = *(const bf16x8*)&Vr[vr * KCH + (((ks * 4 + quad) ^ (vr & 7)) << 3)];
      }
#pragma unroll
      for (int i = 0; i < 2; ++i)
#pragma unroll
        for (int j = 0; j < 4; ++j)
          acc[i][j] =
              __builtin_amdgcn_mfma_f32_16x16x32_bf16(ap[i], bv[j], acc[i][j], 0, 0, 0);
    }
    // 6) rotate V buffers (no second barrier needed: see header comment)
    const int third = 3 - vcur - vnxt;
    vcur = vnxt;
    vnxt = third;
  }

  // rowsum: reduce lane partials over quads, combine two k-halves via LDS
  {
    float vs = rsPart;
    vs += __shfl_xor(vs, 16);
    vs += __shfl_xor(vs, 32);
    if (lane < 16) rsum2[(sq * 16 + l15) * 2 + sk] = vs;
  }
  __syncthreads();  // also drains the final dummy stage

  float rinv[2][4];
#pragma unroll
  for (int i = 0; i < 2; ++i)
#pragma unroll
    for (int r = 0; r < 4; ++r) {
      int row = wp_q * 32 + i * 16 + quad * 4 + r;
      rinv[i][r] = 1.0f / (rsum2[row * 2] + rsum2[row * 2 + 1]);
    }

  __bf16* ob = attn + ((long)b * SEQ + qbase) * H + hbase;
#pragma unroll
  for (int i = 0; i < 2; ++i)
#pragma unroll
    for (int j = 0; j < 4; ++j) {
      const int colL = wp_h * 64 + j * 16 + l15;
#pragma unroll
      for (int r = 0; r < 4; ++r) {
        const int rowL = wp_q * 32 + i * 16 + quad * 4 + r;
        ob[(long)rowL * H + colL] = (__bf16)(acc[i][j][r] * rinv[i][r]);
      }
    }
}

// ---------------- m97-style GEMM + XOR-swizzled LDS: C = A @ Bt^T (+bias) ----
// v2: XCD-aware block remap (T1). Grid must be (8, 64): each XCD gets 8
// contiguous row-panels x all 8 col-blocks, so each 256KB A-panel is fetched
// into exactly one XCD's L2 (was: sprayed across 8 XCDs -> up to 8x A traffic).
// OUTMODE: 0 = fp32 row-major, 1 = bf16 row-major, 2 = bf16 transposed batched
//          (Cout layout [BATCH][N][SEQ], rows are per-batch: row = b*SEQ + rb)
template <int OUTMODE, int HASBIAS>
__global__ __launch_bounds__(256) void gemm_bt(
    const __bf16* __restrict__ A, const __bf16* __restrict__ Bt,
    void* __restrict__ Cout, const float* __restrict__ bias, int M, int N, int K) {
  __shared__ __bf16 Alds[128 * 64];
  __shared__ __bf16 Blds[128 * 64];
  const int tid = threadIdx.x;
  const int lane = tid & 63;
  const int w = tid >> 6;
  const int wm = w >> 1, wn = w & 1;
  const int l15 = lane & 15, quad = lane >> 4;

  // XCD remap (grid == (8,64), 512 blocks, round-robin dispatch):
  const int flat = blockIdx.y * 8 + blockIdx.x;  // 0..511
  const int xcd = flat & 7, idx = flat >> 3;     // idx 0..63
  const int rowPanel = xcd * 8 + (idx >> 3);     // 0..63
  const int colBlk = idx & 7;                    // 0..7
  const long rowBase = (long)rowPanel * 128;
  const long colBase = (long)colBlk * 128;

  const int srow = lane >> 3;                 // 0..7
  const int segsw = ((lane & 7) ^ srow) * 8;  // swizzled global k-seg

  const __bf16* ag[4];
  const __bf16* bg[4];
  __bf16* as_[4];
  __bf16* bs_[4];
#pragma unroll
  for (int j = 0; j < 4; ++j) {
    int r = j * 32 + w * 8;
    ag[j] = A + (rowBase + r + srow) * (long)K + segsw;
    bg[j] = Bt + (colBase + r + srow) * (long)K + segsw;
    as_[j] = &Alds[r * 64 + (lane & 7) * 8];
    bs_[j] = &Blds[r * 64 + (lane & 7) * 8];
  }

  f32x4 acc[4][4];
#pragma unroll
  for (int i = 0; i < 4; ++i)
#pragma unroll
    for (int j = 0; j < 4; ++j) {
      acc[i][j][0] = 0.f; acc[i][j][1] = 0.f; acc[i][j][2] = 0.f; acc[i][j][3] = 0.f;
    }

  const int h7 = l15 & 7;

  for (int k0 = 0; k0 < K; k0 += 64) {
#pragma unroll
    for (int j = 0; j < 4; ++j) {
      async_g2l_16(ag[j], as_[j]);
      async_g2l_16(bg[j], bs_[j]);
      ag[j] += 64;
      bg[j] += 64;
    }
    __syncthreads();
#pragma unroll
    for (int s = 0; s < 2; ++s) {
      const int slot = ((s * 4 + quad) ^ h7) * 8;
      bf16x8 af[4], bfv[4];
#pragma unroll
      for (int i = 0; i < 4; ++i) {
        af[i] = *(const bf16x8*)&Alds[(wm * 64 + i * 16 + l15) * 64 + slot];
        bfv[i] = *(const bf16x8*)&Blds[(wn * 64 + i * 16 + l15) * 64 + slot];
      }
#pragma unroll
      for (int i = 0; i < 4; ++i)
#pragma unroll
        for (int j = 0; j < 4; ++j)
          acc[i][j] =
              __builtin_amdgcn_mfma_f32_16x16x32_bf16(af[i], bfv[j], acc[i][j], 0, 0, 0);
    }
    __syncthreads();
  }

  const long crow0 = rowBase + wm * 64 + quad * 4;
  const long ccol0 = colBase + wn * 64 + l15;
#pragma unroll
  for (int i = 0; i < 4; ++i) {
#pragma unroll
    for (int j = 0; j < 4; ++j) {
      long col = ccol0 + j * 16;
      float bb = HASBIAS ? bias[col] : 0.f;
      if (OUTMODE == 2) {
        long row0 = crow0 + i * 16;          // 4 consecutive rows, same batch
        int bz = (int)(row0 >> 11);          // row / SEQ
        long rb = row0 & (SEQ - 1);
        bf16x4 pv;
#pragma unroll
        for (int r = 0; r < 4; ++r) pv[r] = (__bf16)(acc[i][j][r] + bb);
        *(bf16x4*)&((__bf16*)Cout)[((long)bz * N + col) * SEQ + rb] = pv;
      } else {
#pragma unroll
        for (int r = 0; r < 4; ++r) {
          long row = crow0 + i * 16 + r;
          float val = acc[i][j][r] + bb;
          if (OUTMODE == 0)
            ((float*)Cout)[row * N + col] = val;
          else
            ((__bf16*)Cout)[row * N + col] = (__bf16)val;
        }
      }
    }
  }
}

extern "C" void kernel_launch(void* const* d_in, const int* in_sizes, int n_in,
                              void* d_out, int out_size, void* d_ws, size_t ws_size,
                              hipStream_t stream) {
  const float* x = (const float*)d_in[0];
  const float* Wq = (const float*)d_in[1];
  const float* bq = (const float*)d_in[2];
  const float* Wk = (const float*)d_in[3];
  const float* bk = (const float*)d_in[4];
  const float* Wv = (const float*)d_in[5];
  const float* bv = (const float*)d_in[6];
  const float* We = (const float*)d_in[7];
  const float* be = (const float*)d_in[8];
  const float* Wo = (const float*)d_in[9];
  const float* bo = (const float*)d_in[10];
  float* out = (float*)d_out;

  char* ws = (char*)d_ws;
  size_t o = 0;
  auto alloc = [&](size_t n) {
    size_t r = o;
    o += (n + 255) & ~(size_t)255;
    return r;
  };
  __bf16* xbf = (__bf16*)(ws + alloc((size_t)MROWS * H * 2));  // x hi
  __bf16* v_t = (__bf16*)(ws + alloc((size_t)MROWS * H * 2));  // v^T [B][H][S]
  __bf16* attn = (__bf16*)(ws + alloc((size_t)MROWS * H * 2));
  __bf16* Wvt = (__bf16*)(ws + alloc((size_t)H * H * 2));
  __bf16* Wot = (__bf16*)(ws + alloc((size_t)H * H * 2));
  __bf16* Cth = (__bf16*)(ws + alloc((size_t)32 * H * 2));
  __bf16* Ctl = (__bf16*)(ws + alloc((size_t)32 * H * 2));
  float* dvec = (float*)(ws + alloc(32 * 4));
  __bf16* qq32 = (__bf16*)(ws + alloc((size_t)MROWS * 32 * 2));
  __bf16* kk32 = (__bf16*)(ws + alloc((size_t)MROWS * 32 * 2));
  // Alias (stream-ordered lifetime separation):
  __bf16* xlo = attn;  // x lo part: dead before attn is written (fused_attn)
  if (ws_size < o) return;

  // 1) x -> bf16 hi/lo split
  cvt_split<<<MROWS * H / 1024, 256, 0, stream>>>(x, xbf, xlo, MROWS * H);
  // 2) Wv^T, Wo^T as bf16
  transpose_cvt_f32_bf16<<<dim3(32, 32), 256, 0, stream>>>(Wv, Wvt, H, H);
  transpose_cvt_f32_bf16<<<dim3(32, 32), 256, 0, stream>>>(Wo, Wot, H, H);
  // 3) collapsed embed matrices (bf16 hi/lo, Bt layout) + bias fold
  k2_cqk<<<512, 256, 0, stream>>>(Wq, Wk, We, Cth, Ctl);
  k2b_dvec<<<1, 512, 0, stream>>>(bq, bk, We, be, dvec);
  // 4) unit-norm quantum embeds via MFMA (4-way K-split, 16 waves)
  k3_embed_mfma<<<MROWS / 32, 1024, 0, stream>>>(xbf, xlo, Cth, Ctl, dvec, qq32, kk32);
  // 5) v = x@Wv + bv, written TRANSPOSED per batch -> v_t[b][h][s]
  gemm_bt<2, 1><<<dim3(8, 64), 256, 0, stream>>>(xbf, Wvt, v_t, bv, MROWS, H, H);
  // 6) fused: S^T once per 256h -> exp2(S'^2) -> P@v/rowsum  (bf16 out, 16 waves)
  fused_attn<<<256, 1024, 0, stream>>>(qq32, kk32, v_t, attn);
  // 7) out = attended @ Wo + bo  (fp32 out)
  gemm_bt<0, 1><<<dim3(8, 64), 256, 0, stream>>>(attn, Wot, out, bo, MROWS, H, H);
}